// Round 10
// baseline (301.117 us; speedup 1.0000x reference)
//
#include <hip/hip_runtime.h>
#include <math.h>

#define NN 50000
#define NE 800000
#define SLOPE 0.2f
#define NEGX (-1e30f)
#define CH 8192

typedef _Float16 h8 __attribute__((ext_vector_type(8)));
typedef _Float16 h2 __attribute__((ext_vector_type(2)));
typedef float f8 __attribute__((ext_vector_type(8)));
typedef float v4f __attribute__((ext_vector_type(4)));

__device__ __forceinline__ h8 hzero(){ h8 z = {0,0,0,0,0,0,0,0}; return z; }
__device__ __forceinline__ f8 fzero(){ f8 z = {0,0,0,0,0,0,0,0}; return z; }

// ---------------- fused weight pack (fp16 fragment order) + edge histogram ----
__device__ __forceinline__ void pack_one(const float* __restrict__ W,
                                         _Float16* __restrict__ Wp,
                                         int DO, int K, int NT, int t){
  int KC = K >> 5;
  if (t >= NT * KC * 64) return;
  int lane = t & 63;
  int rest = t >> 6;
  int c  = rest % KC;
  int nt = rest / KC;
  int col = nt * 16 + (lane & 15);
  int k0  = c * 32 + ((lane >> 4) << 3);
  _Float16 o[8];
#pragma unroll
  for (int j = 0; j < 8; j++){
    float v = (col < DO) ? W[(k0 + j) * DO + col] : 0.f;
    o[j] = (_Float16)v;
  }
  *(ulonglong2*)(Wp + (size_t)t * 8) = *(ulonglong2*)o;
}

__global__ __launch_bounds__(256) void k_pack_hist(
    const float* W1l, const float* W1r, const float* W2l,
    const float* W2r, const float* W3l, const float* W3r,
    _Float16* p1l, _Float16* p1r, _Float16* p2l,
    _Float16* p2r, _Float16* p3l, _Float16* p3r,
    const int* __restrict__ ei, int* __restrict__ gbp){
  __shared__ int h[256];
  int b = blockIdx.x, t = threadIdx.x;
  if (b < 44){
    if      (b < 16) pack_one(W1l, p1l, 128, 256, 8, (b     ) * 256 + t);
    else if (b < 32) pack_one(W1r, p1r, 128, 256, 8, (b - 16) * 256 + t);
    else if (b < 36) pack_one(W2l, p2l,  64, 128, 4, (b - 32) * 256 + t);
    else if (b < 40) pack_one(W2r, p2r,  64, 128, 4, (b - 36) * 256 + t);
    else if (b < 42) pack_one(W3l, p3l,  40,  64, 3, (b - 40) * 256 + t);
    else             pack_one(W3r, p3r,  40,  64, 3, (b - 42) * 256 + t);
  } else {
    int hb = b - 44;                 // 0..63, each owns 12500 edges
    h[t] = 0;
    __syncthreads();
    int e0 = hb * 12500;
    for (int i = t; i < 12500; i += 256)
      atomicAdd(&h[ei[NE + e0 + i] >> 8], 1);
    __syncthreads();
    gbp[hb * 256 + t] = h[t];        // non-atomic partials
  }
}

__global__ __launch_bounds__(256) void k_scan(const int* __restrict__ gbp,
                                              int* __restrict__ base,
                                              int* __restrict__ bcur,
                                              int* __restrict__ row_ptr){
  __shared__ int s[256];
  int t = threadIdx.x;
  int v = 0;
#pragma unroll 8
  for (int i = 0; i < 64; i++) v += gbp[i * 256 + t];
  s[t] = v; __syncthreads();
  for (int off = 1; off < 256; off <<= 1){
    int a = (t >= off) ? s[t - off] : 0;
    __syncthreads(); s[t] += a; __syncthreads();
  }
  int ex = s[t] - v;
  base[t] = ex;
  bcur[t] = ex;
  if (t == 255){ base[256] = s[255]; row_ptr[NN] = s[255]; }
}

// pack: src (16b) | dstLow (8b) << 16 | bucket (8b) << 24
__global__ __launch_bounds__(256) void k_bscatter(const int* __restrict__ ei,
                                                  int* __restrict__ bcur,
                                                  unsigned* __restrict__ pk_out){
  __shared__ unsigned pk[CH];
  __shared__ int h[256];
  int t = threadIdx.x;
  int e0 = blockIdx.x * CH;
  h[t] = 0;
  __syncthreads();
  int n = NE - e0; if (n > CH) n = CH;
  for (int i = t; i < n; i += 256){
    int e = e0 + i;
    int s = ei[e], d = ei[NE + e];
    pk[i] = (unsigned)s | ((unsigned)(d & 255) << 16) | ((unsigned)(d >> 8) << 24);
    atomicAdd(&h[d >> 8], 1);
  }
  __syncthreads();
  int c = h[t];
  if (c) h[t] = atomicAdd(&bcur[t], c);
  __syncthreads();
  for (int i = t; i < n; i += 256){
    unsigned u = pk[i];
    int pos = atomicAdd(&h[u >> 24], 1);
    pk_out[pos] = u;
  }
}

__global__ __launch_bounds__(256) void k_bcsr(const unsigned* __restrict__ pk,
                                              const int* __restrict__ base,
                                              int* __restrict__ row_ptr,
                                              int* __restrict__ csr_src){
  __shared__ int h[256], s[256];
  int t = threadIdx.x;
  int b = blockIdx.x;
  int lo = base[b], hi = base[b + 1];
  h[t] = 0;
  __syncthreads();
  for (int i = lo + t; i < hi; i += 256)
    atomicAdd(&h[(pk[i] >> 16) & 255], 1);
  __syncthreads();
  int v = h[t];
  s[t] = v; __syncthreads();
  for (int off = 1; off < 256; off <<= 1){
    int a = (t >= off) ? s[t - off] : 0;
    __syncthreads(); s[t] += a; __syncthreads();
  }
  int ex = lo + s[t] - v;
  int node = b * 256 + t;
  if (node < NN) row_ptr[node] = ex;
  h[t] = ex;
  __syncthreads();
  for (int i = lo + t; i < hi; i += 256){
    unsigned u = pk[i];
    int pos = atomicAdd(&h[(u >> 16) & 255], 1);
    csr_src[pos] = (int)(u & 0xFFFFu);
  }
}

// ---------------- Direct-load MFMA dual GEMM (no LDS, no barrier) -------------
template<typename TI, int K, int DO>
__global__ __launch_bounds__(256, 4) void gemm_direct(
    const TI* __restrict__ X,
    const _Float16* __restrict__ Wpl, const float* __restrict__ bl,
    const _Float16* __restrict__ Wpr, const float* __restrict__ br,
    _Float16* __restrict__ Yl, _Float16* __restrict__ Yr)
{
  constexpr int KC = K / 32;
  constexpr int NT = (DO + 15) / 16;
  int lane = threadIdx.x & 63;
  int wv   = threadIdx.x >> 6;
  int row0 = (blockIdx.x * 4 + wv) * 16;   // m-tile base
  int arow = lane & 15;
  int koff = lane >> 4;
  int lrow = row0 + arow;
  int crow = (lrow < NN) ? lrow : 0;       // clamp loads; stores masked

  h8 afrag[KC];
  if constexpr (sizeof(TI) == 4){
    const float* Xr = (const float*)X + (size_t)crow * K + koff * 8;
#pragma unroll
    for (int c = 0; c < KC; c++){
      float4 v0 = *reinterpret_cast<const float4*>(Xr + c * 32);
      float4 v1 = *reinterpret_cast<const float4*>(Xr + c * 32 + 4);
      h8 a;
      a[0]=(_Float16)v0.x; a[1]=(_Float16)v0.y; a[2]=(_Float16)v0.z; a[3]=(_Float16)v0.w;
      a[4]=(_Float16)v1.x; a[5]=(_Float16)v1.y; a[6]=(_Float16)v1.z; a[7]=(_Float16)v1.w;
      afrag[c] = a;
    }
  } else {
    const _Float16* Xr = (const _Float16*)X + (size_t)crow * K + koff * 8;
#pragma unroll
    for (int c = 0; c < KC; c++)
      afrag[c] = *reinterpret_cast<const h8*>(Xr + c * 32);
  }

#pragma unroll
  for (int side = 0; side < 2; side++){
    const _Float16* Wp = side ? Wpr : Wpl;
    const float* bias = side ? br : bl;
    _Float16* Y = side ? Yr : Yl;
#pragma unroll
    for (int nt = 0; nt < NT; nt++){
      v4f acc = {0.f, 0.f, 0.f, 0.f};
#pragma unroll
      for (int c = 0; c < KC; c++){
        h8 b = *reinterpret_cast<const h8*>(Wp + (size_t)((nt * KC + c) * 64 + lane) * 8);
        acc = __builtin_amdgcn_mfma_f32_16x16x32_f16(afrag[c], b, acc, 0, 0, 0);
      }
      int col = nt * 16 + arow;            // C/D: col = lane&15
      if (col < DO){
        float bv = bias[col];
        int rbase = row0 + koff * 4;       // C/D: row = (lane>>4)*4 + reg
#pragma unroll
        for (int r = 0; r < 4; r++){
          int orow = rbase + r;
          if (orow < NN) Y[(size_t)orow * DO + col] = (_Float16)(acc[r] + bv);
        }
      }
    }
  }
}

// ---------------- agg helpers ----------------
__device__ __forceinline__ float edge_logit(h8 x, h8 xrv, h8 attv){
  h8 t = x + xrv;
  h8 l = __builtin_elementwise_max(t, t * (_Float16)SLOPE);
  const h2* lp = (const h2*)&l;
  const h2* ap = (const h2*)&attv;
  h2 d = lp[0] * ap[0];
  d += lp[1] * ap[1];
  d += lp[2] * ap[2];
  d += lp[3] * ap[3];
  return (float)d[0] + (float)d[1];
}

template<int LPG>
__device__ __forceinline__ float gsum(float v){
#pragma unroll
  for (int off = 1; off < LPG; off <<= 1) v += __shfl_xor(v, off, 64);
  return v;
}
template<int LPG>
__device__ __forceinline__ void gsum4(float& a, float& b, float& c, float& d){
#pragma unroll
  for (int off = 1; off < LPG; off <<= 1){
    a += __shfl_xor(a, off, 64);
    b += __shfl_xor(b, off, 64);
    c += __shfl_xor(c, off, 64);
    d += __shfl_xor(d, off, 64);
  }
}
template<int LPG>
__device__ __forceinline__ float gmax(float v){
#pragma unroll
  for (int off = 1; off < LPG; off <<= 1) v = fmaxf(v, __shfl_xor(v, off, 64));
  return v;
}

// 4-state online aggregation over a group's edge list (no max-subtract:
// Glorot-scale logits are O(±8); fp32 exp overflows at 88).
// MASK=false: all lanes active (LPG*8==DO).
template<int DO, int LPG, bool MASK>
__device__ __forceinline__ void agg_edges(
    const _Float16* __restrict__ xl, const int* __restrict__ csr_src,
    int e0, int e1, int cbase, bool ok, h8 xrv, h8 attv,
    float& den, f8& acc)
{
  f8 aA = acc, aB = fzero(), aC = fzero(), aD = fzero();
  float dA = den, dB = 0.f, dC = 0.f, dD = 0.f;
  int e = e0;
  for (; e + 3 < e1; e += 4){
    int sA = csr_src[e], sB = csr_src[e + 1], sC = csr_src[e + 2], sD = csr_src[e + 3];
    h8 xA, xB, xC, xD;
    if (!MASK || ok){
      xA = *reinterpret_cast<const h8*>(xl + sA * DO + cbase);
      xB = *reinterpret_cast<const h8*>(xl + sB * DO + cbase);
      xC = *reinterpret_cast<const h8*>(xl + sC * DO + cbase);
      xD = *reinterpret_cast<const h8*>(xl + sD * DO + cbase);
    } else { xA = xB = xC = xD = hzero(); }
    float pA = edge_logit(xA, xrv, attv);
    float pB = edge_logit(xB, xrv, attv);
    float pC = edge_logit(xC, xrv, attv);
    float pD = edge_logit(xD, xrv, attv);
    gsum4<LPG>(pA, pB, pC, pD);
    float wA = __expf(pA), wB = __expf(pB), wC = __expf(pC), wD = __expf(pD);
    dA += wA; dB += wB; dC += wC; dD += wD;
    aA += __builtin_convertvector(xA, f8) * wA;
    aB += __builtin_convertvector(xB, f8) * wB;
    aC += __builtin_convertvector(xC, f8) * wC;
    aD += __builtin_convertvector(xD, f8) * wD;
  }
  for (; e < e1; e++){
    int sA = csr_src[e];
    h8 xA = (!MASK || ok) ? *reinterpret_cast<const h8*>(xl + sA * DO + cbase) : hzero();
    float pA = gsum<LPG>(edge_logit(xA, xrv, attv));
    float w = __expf(pA);
    dA += w;
    aA += __builtin_convertvector(xA, f8) * w;
  }
  den = (dA + dB) + (dC + dD);
  acc = (aA + aB) + (aC + aD);
}

// ---------------- Fused agg(layer l) + gemm(layer l+1) ----------------
// Requires LPG*8 == DO (all lanes active). Block = 4 waves = NPB nodes;
// agg writes h rows to LDS (+8-half pad); waves then compute the next
// layer's dual GEMM straight from LDS.
template<int DO, int LPG, int DO2>
__global__ __launch_bounds__(256) void agg_gemm(
    const _Float16* __restrict__ xl, const _Float16* __restrict__ xr,
    const int* __restrict__ csr_src, const int* __restrict__ row_ptr,
    const float* __restrict__ att, const float* __restrict__ bias,
    const _Float16* __restrict__ Wpl2, const float* __restrict__ bl2,
    const _Float16* __restrict__ Wpr2, const float* __restrict__ br2,
    _Float16* __restrict__ Yl, _Float16* __restrict__ Yr)
{
  constexpr int G = 64 / LPG;
  constexpr int NPB = 4 * G;            // nodes per block
  constexpr int LK = DO + 8;            // padded LDS row stride (halves)
  constexpr int KC2 = DO / 32;
  constexpr int NT2 = (DO2 + 15) / 16;
  constexpr int MT = NPB / 16;          // m-tiles per block (1 or 2)
  __shared__ _Float16 hs[NPB * LK];

  int lane = threadIdx.x & 63;
  int wid  = threadIdx.x >> 6;
  int g = lane / LPG, p = lane % LPG;
  int nodeLocal = wid * G + g;
  int node = blockIdx.x * NPB + nodeLocal;
  int cbase = p * 8;
  bool nvalid = node < NN;
  int nodeC = nvalid ? node : 0;

  // ---- agg phase ----
  h8 attv, xrv, xlv;
  {
    float4 a0 = *reinterpret_cast<const float4*>(att + cbase);
    float4 a1 = *reinterpret_cast<const float4*>(att + cbase + 4);
    attv[0]=(_Float16)a0.x; attv[1]=(_Float16)a0.y; attv[2]=(_Float16)a0.z; attv[3]=(_Float16)a0.w;
    attv[4]=(_Float16)a1.x; attv[5]=(_Float16)a1.y; attv[6]=(_Float16)a1.z; attv[7]=(_Float16)a1.w;
    xrv = *reinterpret_cast<const h8*>(xr + nodeC * DO + cbase);
    xlv = *reinterpret_cast<const h8*>(xl + nodeC * DO + cbase);
  }
  float s = gsum<LPG>(edge_logit(xlv, xrv, attv));
  float wS = __expf(s);
  float den = wS;
  f8 acc = __builtin_convertvector(xlv, f8) * wS;

  int e0 = row_ptr[nodeC];
  int e1 = nvalid ? row_ptr[nodeC + 1] : e0;
  agg_edges<DO, LPG, false>(xl, csr_src, e0, e1, cbase, true, xrv, attv, den, acc);

  {
    float inv = 1.0f / den;
    f8 vv;
#pragma unroll
    for (int j = 0; j < 8; j++)
      vv[j] = fmaxf(fmaf(acc[j], inv, bias[cbase + j]), 0.f);
    h8 ho = __builtin_convertvector(vv, h8);
    *reinterpret_cast<h8*>(&hs[nodeLocal * LK + cbase]) = ho;
  }
  __syncthreads();

  // ---- gemm phase: next layer, A from LDS, B from packed W (L2) ----
  int arow = lane & 15;
  int koff = lane >> 4;
  int mt = (MT == 1) ? 0 : (wid >> 1);
  h8 afrag[KC2];
#pragma unroll
  for (int c = 0; c < KC2; c++)
    afrag[c] = *reinterpret_cast<const h8*>(&hs[(mt * 16 + arow) * LK + koff * 8 + c * 32]);

  int row0 = blockIdx.x * NPB + mt * 16;
  int side = wid & 1;
  const _Float16* Wp = side ? Wpr2 : Wpl2;
  const float* bias2 = side ? br2 : bl2;
  _Float16* Y = side ? Yr : Yl;
  int nt_begin = (MT == 1) ? (wid >> 1) * (NT2 / 2) : 0;
  int nt_end   = (MT == 1) ? nt_begin + NT2 / 2 : NT2;
  for (int nt = nt_begin; nt < nt_end; nt++){
    v4f acc2 = {0.f, 0.f, 0.f, 0.f};
#pragma unroll
    for (int c = 0; c < KC2; c++){
      h8 b = *reinterpret_cast<const h8*>(Wp + (size_t)((nt * KC2 + c) * 64 + lane) * 8);
      acc2 = __builtin_amdgcn_mfma_f32_16x16x32_f16(afrag[c], b, acc2, 0, 0, 0);
    }
    int col = nt * 16 + arow;
    if (col < DO2){
      float bv = bias2[col];
      int rbase = row0 + koff * 4;
#pragma unroll
      for (int r = 0; r < 4; r++){
        int orow = rbase + r;
        if (orow < NN) Y[(size_t)orow * DO2 + col] = (_Float16)(acc2[r] + bv);
      }
    }
  }
}

// ---------------- Final GATv2 aggregate + bias + log_softmax ----------------
template<int DO, int LPG>
__global__ __launch_bounds__(256) void gat_agg_out(
    const _Float16* __restrict__ xl, const _Float16* __restrict__ xr,
    const int* __restrict__ csr_src, const int* __restrict__ row_ptr,
    const float* __restrict__ att, const float* __restrict__ bias,
    float* __restrict__ out)
{
  constexpr int G = 64 / LPG;
  int lane = threadIdx.x & 63;
  int wv = (blockIdx.x * 256 + threadIdx.x) >> 6;
  int g = lane / LPG;
  int p = lane % LPG;
  int node = wv * G + g;
  if (node >= NN) return;
  int cbase = p * 8;
  bool ok = (cbase < DO);

  h8 attv = hzero(), xrv = hzero(), xlv = hzero();
  if (ok){
    float4 a0 = *reinterpret_cast<const float4*>(att + cbase);
    float4 a1 = *reinterpret_cast<const float4*>(att + cbase + 4);
    attv[0]=(_Float16)a0.x; attv[1]=(_Float16)a0.y; attv[2]=(_Float16)a0.z; attv[3]=(_Float16)a0.w;
    attv[4]=(_Float16)a1.x; attv[5]=(_Float16)a1.y; attv[6]=(_Float16)a1.z; attv[7]=(_Float16)a1.w;
    xrv = *reinterpret_cast<const h8*>(xr + node * DO + cbase);
    xlv = *reinterpret_cast<const h8*>(xl + node * DO + cbase);
  }

  float s = gsum<LPG>(edge_logit(xlv, xrv, attv));
  float wS = __expf(s);
  float den = wS;
  f8 acc = __builtin_convertvector(xlv, f8) * wS;

  int e0 = row_ptr[node], e1 = row_ptr[node + 1];
  agg_edges<DO, LPG, true>(xl, csr_src, e0, e1, cbase, ok, xrv, attv, den, acc);

  float inv = 1.0f / den;
  float v[8]; float lmax = NEGX;
#pragma unroll
  for (int j = 0; j < 8; j++){
    v[j] = ok ? fmaf(acc[j], inv, bias[cbase + j]) : NEGX;
    lmax = fmaxf(lmax, v[j]);
  }
  lmax = gmax<LPG>(lmax);
  float lsum = 0.f;
#pragma unroll
  for (int j = 0; j < 8; j++) lsum += __expf(v[j] - lmax);   // idle lanes: exp(NEGX)=0
  lsum = gsum<LPG>(lsum);
  if (ok){
    float lg = lmax + __logf(lsum);
    float* op = (float*)out + node * DO + cbase;
    float4 o0, o1;
    o0.x = v[0] - lg; o0.y = v[1] - lg; o0.z = v[2] - lg; o0.w = v[3] - lg;
    o1.x = v[4] - lg; o1.y = v[5] - lg; o1.z = v[6] - lg; o1.w = v[7] - lg;
    *reinterpret_cast<float4*>(op) = o0;
    *reinterpret_cast<float4*>(op + 4) = o1;
  }
}

extern "C" void kernel_launch(void* const* d_in, const int* in_sizes, int n_in,
                              void* d_out, int out_size, void* d_ws, size_t ws_size,
                              hipStream_t stream) {
  const float* x   = (const float*)d_in[0];
  const int*   ei  = (const int*)d_in[1];
  const float* W1l = (const float*)d_in[2];  const float* W1r = (const float*)d_in[3];
  const float* b1l = (const float*)d_in[4];  const float* b1r = (const float*)d_in[5];
  const float* a1  = (const float*)d_in[6];  const float* c1  = (const float*)d_in[7];
  const float* W2l = (const float*)d_in[8];  const float* W2r = (const float*)d_in[9];
  const float* b2l = (const float*)d_in[10]; const float* b2r = (const float*)d_in[11];
  const float* a2  = (const float*)d_in[12]; const float* c2  = (const float*)d_in[13];
  const float* W3l = (const float*)d_in[14]; const float* W3r = (const float*)d_in[15];
  const float* b3l = (const float*)d_in[16]; const float* b3r = (const float*)d_in[17];
  const float* a3  = (const float*)d_in[18]; const float* c3  = (const float*)d_in[19];
  float* outp = (float*)d_out;

  // workspace layout (16B-aligned segments)
  _Float16* xl1 = (_Float16*)d_ws;        // 50000*128
  _Float16* xr1 = xl1 + 6400000;
  _Float16* xl2 = xr1 + 6400000;          // 50000*64
  _Float16* xr2 = xl2 + 3200000;
  _Float16* xl3 = xr2 + 3200000;          // 50000*40
  _Float16* xr3 = xl3 + 2000000;
  _Float16* wp1l = xr3 + 2000000;         // packed weights (fp16)
  _Float16* wp1r = wp1l + 32768;
  _Float16* wp2l = wp1r + 32768;
  _Float16* wp2r = wp2l + 8192;
  _Float16* wp3l = wp2r + 8192;
  _Float16* wp3r = wp3l + 3072;
  unsigned* pk   = (unsigned*)(wp3r + 3072);   // 800000
  int* csr_src   = (int*)(pk + NE);            // 800000
  int* row_ptr   = csr_src + NE;               // 50001
  int* gbp       = row_ptr + 50001;            // 64*256 partial hist
  int* base      = gbp + 16384;                // 257
  int* bcur      = base + 257;                 // 256

  const int GB = (NN + 63) / 64;          // 782 gemm1 blocks (64 rows, 4 waves)
  const int SB = (NE + CH - 1) / CH;      // 98 scatter blocks
  const int FB1 = (NN + 15) / 16;         // fused agg1+gemm2: 16 nodes/block
  const int FB2 = (NN + 31) / 32;         // fused agg2+gemm3: 32 nodes/block
  const int AB3 = (NN + 31) / 32;         // agg3: 32 nodes/block (LPG=8)

  // pack weights + partial edge histogram (one launch)
  k_pack_hist<<<108, 256, 0, stream>>>(W1l, W1r, W2l, W2r, W3l, W3r,
                                       wp1l, wp1r, wp2l, wp2r, wp3l, wp3r,
                                       ei, gbp);
  k_scan<<<1, 256, 0, stream>>>(gbp, base, bcur, row_ptr);
  k_bscatter<<<SB, 256, 0, stream>>>(ei, bcur, pk);
  k_bcsr<<<196, 256, 0, stream>>>(pk, base, row_ptr, csr_src);

  // layer 1 GEMM: x (fp32) -> xl1, xr1
  gemm_direct<float,256,128><<<GB, 256, 0, stream>>>(x, wp1l, b1l, wp1r, b1r, xl1, xr1);

  // fused: agg layer1 (relu) + gemm layer2 -> xl2, xr2
  agg_gemm<128,16,64><<<FB1, 256, 0, stream>>>(xl1, xr1, csr_src, row_ptr,
                                               a1, c1, wp2l, b2l, wp2r, b2r, xl2, xr2);

  // fused: agg layer2 (relu) + gemm layer3 -> xl3, xr3
  agg_gemm<64,8,40><<<FB2, 256, 0, stream>>>(xl2, xr2, csr_src, row_ptr,
                                             a2, c2, wp3l, b3l, wp3r, b3r, xl3, xr3);

  // final: agg layer3 + bias + log_softmax -> out
  gat_agg_out<40,8><<<AB3, 256, 0, stream>>>(xl3, xr3, csr_src, row_ptr, a3, c3, outp);
}

// Round 11
// 296.421 us; speedup vs baseline: 1.0158x; 1.0158x over previous
//
#include <hip/hip_runtime.h>
#include <math.h>

#define NN 50000
#define NE 800000
#define SLOPE 0.2f
#define NEGX (-1e30f)
#define CH 8192

typedef _Float16 h8 __attribute__((ext_vector_type(8)));
typedef _Float16 h2 __attribute__((ext_vector_type(2)));
typedef float f8 __attribute__((ext_vector_type(8)));
typedef float v4f __attribute__((ext_vector_type(4)));

__device__ __forceinline__ h8 hzero(){ h8 z = {0,0,0,0,0,0,0,0}; return z; }

// ---------------- fused weight pack (fp16 fragment order) + edge histogram ----
__device__ __forceinline__ void pack_one(const float* __restrict__ W,
                                         _Float16* __restrict__ Wp,
                                         int DO, int K, int NT, int t){
  int KC = K >> 5;
  if (t >= NT * KC * 64) return;
  int lane = t & 63;
  int rest = t >> 6;
  int c  = rest % KC;
  int nt = rest / KC;
  int col = nt * 16 + (lane & 15);
  int k0  = c * 32 + ((lane >> 4) << 3);
  _Float16 o[8];
#pragma unroll
  for (int j = 0; j < 8; j++){
    float v = (col < DO) ? W[(k0 + j) * DO + col] : 0.f;
    o[j] = (_Float16)v;
  }
  *(ulonglong2*)(Wp + (size_t)t * 8) = *(ulonglong2*)o;
}

__global__ __launch_bounds__(256) void k_pack_hist(
    const float* W1l, const float* W1r, const float* W2l,
    const float* W2r, const float* W3l, const float* W3r,
    _Float16* p1l, _Float16* p1r, _Float16* p2l,
    _Float16* p2r, _Float16* p3l, _Float16* p3r,
    const int* __restrict__ ei, int* __restrict__ gbp){
  __shared__ int h[256];
  int b = blockIdx.x, t = threadIdx.x;
  if (b < 44){
    if      (b < 16) pack_one(W1l, p1l, 128, 256, 8, (b     ) * 256 + t);
    else if (b < 32) pack_one(W1r, p1r, 128, 256, 8, (b - 16) * 256 + t);
    else if (b < 36) pack_one(W2l, p2l,  64, 128, 4, (b - 32) * 256 + t);
    else if (b < 40) pack_one(W2r, p2r,  64, 128, 4, (b - 36) * 256 + t);
    else if (b < 42) pack_one(W3l, p3l,  40,  64, 3, (b - 40) * 256 + t);
    else             pack_one(W3r, p3r,  40,  64, 3, (b - 42) * 256 + t);
  } else {
    int hb = b - 44;                 // 0..63, each owns 12500 edges
    h[t] = 0;
    __syncthreads();
    int e0 = hb * 12500;
    for (int i = t; i < 12500; i += 256)
      atomicAdd(&h[ei[NE + e0 + i] >> 8], 1);
    __syncthreads();
    gbp[hb * 256 + t] = h[t];        // non-atomic partials
  }
}

__global__ __launch_bounds__(256) void k_scan(const int* __restrict__ gbp,
                                              int* __restrict__ base,
                                              int* __restrict__ bcur,
                                              int* __restrict__ row_ptr,
                                              int* __restrict__ dhist){
  __shared__ int s[256];
  int t = threadIdx.x;
  if (t < 64) dhist[t] = 0;          // zero degree-histogram for k_bcsr
  int v = 0;
#pragma unroll 8
  for (int i = 0; i < 64; i++) v += gbp[i * 256 + t];
  s[t] = v; __syncthreads();
  for (int off = 1; off < 256; off <<= 1){
    int a = (t >= off) ? s[t - off] : 0;
    __syncthreads(); s[t] += a; __syncthreads();
  }
  int ex = s[t] - v;
  base[t] = ex;
  bcur[t] = ex;
  if (t == 255){ base[256] = s[255]; row_ptr[NN] = s[255]; }
}

// pack: src (16b) | dstLow (8b) << 16 | bucket (8b) << 24
__global__ __launch_bounds__(256) void k_bscatter(const int* __restrict__ ei,
                                                  int* __restrict__ bcur,
                                                  unsigned* __restrict__ pk_out){
  __shared__ unsigned pk[CH];
  __shared__ int h[256];
  int t = threadIdx.x;
  int e0 = blockIdx.x * CH;
  h[t] = 0;
  __syncthreads();
  int n = NE - e0; if (n > CH) n = CH;
  for (int i = t; i < n; i += 256){
    int e = e0 + i;
    int s = ei[e], d = ei[NE + e];
    pk[i] = (unsigned)s | ((unsigned)(d & 255) << 16) | ((unsigned)(d >> 8) << 24);
    atomicAdd(&h[d >> 8], 1);
  }
  __syncthreads();
  int c = h[t];
  if (c) h[t] = atomicAdd(&bcur[t], c);
  __syncthreads();
  for (int i = t; i < n; i += 256){
    unsigned u = pk[i];
    int pos = atomicAdd(&h[u >> 24], 1);
    pk_out[pos] = u;
  }
}

__global__ __launch_bounds__(256) void k_bcsr(const unsigned* __restrict__ pk,
                                              const int* __restrict__ base,
                                              int* __restrict__ row_ptr,
                                              int* __restrict__ csr_src,
                                              int* __restrict__ dhist){
  __shared__ int h[256], s[256], dh[64];
  int t = threadIdx.x;
  int b = blockIdx.x;
  int lo = base[b], hi = base[b + 1];
  h[t] = 0;
  if (t < 64) dh[t] = 0;
  __syncthreads();
  for (int i = lo + t; i < hi; i += 256)
    atomicAdd(&h[(pk[i] >> 16) & 255], 1);
  __syncthreads();
  int v = h[t];
  s[t] = v; __syncthreads();
  for (int off = 1; off < 256; off <<= 1){
    int a = (t >= off) ? s[t - off] : 0;
    __syncthreads(); s[t] += a; __syncthreads();
  }
  int ex = lo + s[t] - v;
  int node = b * 256 + t;
  if (node < NN){
    row_ptr[node] = ex;
    atomicAdd(&dh[v < 63 ? v : 63], 1);   // degree histogram (block-local)
  }
  h[t] = ex;
  __syncthreads();
  if (t < 64 && dh[t]) atomicAdd(&dhist[t], dh[t]);
  for (int i = lo + t; i < hi; i += 256){
    unsigned u = pk[i];
    int pos = atomicAdd(&h[(u >> 16) & 255], 1);
    csr_src[pos] = (int)(u & 0xFFFFu);
  }
}

// scan the 64-bin degree histogram -> cursors
__global__ __launch_bounds__(64) void k_dscan(const int* __restrict__ dhist,
                                              int* __restrict__ dcur){
  __shared__ int s[64];
  int t = threadIdx.x;
  int v = dhist[t];
  s[t] = v; __syncthreads();
  for (int off = 1; off < 64; off <<= 1){
    int a = (t >= off) ? s[t - off] : 0;
    __syncthreads(); s[t] += a; __syncthreads();
  }
  dcur[t] = s[t] - v;
}

// counting-sort node IDs by (clamped) degree -> perm
__global__ __launch_bounds__(256) void k_dscatter(const int* __restrict__ row_ptr,
                                                  int* __restrict__ dcur,
                                                  int* __restrict__ perm){
  __shared__ int dh[64];
  int t = threadIdx.x;
  int node = blockIdx.x * 256 + t;
  int bin = -1, rank = 0;
  if (t < 64) dh[t] = 0;
  __syncthreads();
  if (node < NN){
    int deg = row_ptr[node + 1] - row_ptr[node];
    bin = deg < 63 ? deg : 63;
    rank = atomicAdd(&dh[bin], 1);
  }
  __syncthreads();
  if (t < 64){ int c = dh[t]; dh[t] = c ? atomicAdd(&dcur[t], c) : 0; }
  __syncthreads();
  if (bin >= 0) perm[dh[bin] + rank] = node;
}

// ---------------- Direct-load MFMA dual GEMM (no LDS, no barrier) -------------
template<typename TI, int K, int DO>
__global__ __launch_bounds__(256, 4) void gemm_direct(
    const TI* __restrict__ X,
    const _Float16* __restrict__ Wpl, const float* __restrict__ bl,
    const _Float16* __restrict__ Wpr, const float* __restrict__ br,
    _Float16* __restrict__ Yl, _Float16* __restrict__ Yr)
{
  constexpr int KC = K / 32;
  constexpr int NT = (DO + 15) / 16;
  int lane = threadIdx.x & 63;
  int wv   = threadIdx.x >> 6;
  int row0 = (blockIdx.x * 4 + wv) * 16;   // m-tile base
  int arow = lane & 15;
  int koff = lane >> 4;
  int lrow = row0 + arow;
  int crow = (lrow < NN) ? lrow : 0;       // clamp loads; stores masked

  h8 afrag[KC];
  if constexpr (sizeof(TI) == 4){
    const float* Xr = (const float*)X + (size_t)crow * K + koff * 8;
#pragma unroll
    for (int c = 0; c < KC; c++){
      float4 v0 = *reinterpret_cast<const float4*>(Xr + c * 32);
      float4 v1 = *reinterpret_cast<const float4*>(Xr + c * 32 + 4);
      h8 a;
      a[0]=(_Float16)v0.x; a[1]=(_Float16)v0.y; a[2]=(_Float16)v0.z; a[3]=(_Float16)v0.w;
      a[4]=(_Float16)v1.x; a[5]=(_Float16)v1.y; a[6]=(_Float16)v1.z; a[7]=(_Float16)v1.w;
      afrag[c] = a;
    }
  } else {
    const _Float16* Xr = (const _Float16*)X + (size_t)crow * K + koff * 8;
#pragma unroll
    for (int c = 0; c < KC; c++)
      afrag[c] = *reinterpret_cast<const h8*>(Xr + c * 32);
  }

#pragma unroll
  for (int side = 0; side < 2; side++){
    const _Float16* Wp = side ? Wpr : Wpl;
    const float* bias = side ? br : bl;
    _Float16* Y = side ? Yr : Yl;
#pragma unroll
    for (int nt = 0; nt < NT; nt++){
      v4f acc = {0.f, 0.f, 0.f, 0.f};
#pragma unroll
      for (int c = 0; c < KC; c++){
        h8 b = *reinterpret_cast<const h8*>(Wp + (size_t)((nt * KC + c) * 64 + lane) * 8);
        acc = __builtin_amdgcn_mfma_f32_16x16x32_f16(afrag[c], b, acc, 0, 0, 0);
      }
      int col = nt * 16 + arow;            // C/D: col = lane&15
      if (col < DO){
        float bv = bias[col];
        int rbase = row0 + koff * 4;       // C/D: row = (lane>>4)*4 + reg
#pragma unroll
        for (int r = 0; r < 4; r++){
          int orow = rbase + r;
          if (orow < NN) Y[(size_t)orow * DO + col] = (_Float16)(acc[r] + bv);
        }
      }
    }
  }
}

// ---------------- agg helpers ----------------
__device__ __forceinline__ float edge_logit(h8 x, h8 xrv, h8 attv){
  h8 t = x + xrv;
  h8 l = __builtin_elementwise_max(t, t * (_Float16)SLOPE);
  const h2* lp = (const h2*)&l;
  const h2* ap = (const h2*)&attv;
  h2 d = lp[0] * ap[0];
  d += lp[1] * ap[1];
  d += lp[2] * ap[2];
  d += lp[3] * ap[3];
  return (float)d[0] + (float)d[1];
}

template<int LPG>
__device__ __forceinline__ float gsum(float v){
#pragma unroll
  for (int off = 1; off < LPG; off <<= 1) v += __shfl_xor(v, off, 64);
  return v;
}
template<int LPG>
__device__ __forceinline__ void gsum2(float& a, float& b){
#pragma unroll
  for (int off = 1; off < LPG; off <<= 1){
    a += __shfl_xor(a, off, 64);
    b += __shfl_xor(b, off, 64);
  }
}
template<int LPG>
__device__ __forceinline__ float gmax(float v){
#pragma unroll
  for (int off = 1; off < LPG; off <<= 1) v = fmaxf(v, __shfl_xor(v, off, 64));
  return v;
}

// 2-state online aggregation (no max-subtract: Glorot logits O(+-8), exp safe)
template<int DO, int LPG, bool MASK>
__device__ __forceinline__ void agg_edges(
    const _Float16* __restrict__ xl, const int* __restrict__ csr_src,
    int e0, int e1, int cbase, bool ok, h8 xrv, h8 attv,
    float& denA, float& denB, float* accA, float* accB)
{
  int e = e0;
  for (; e + 1 < e1; e += 2){
    int sA = csr_src[e], sB = csr_src[e + 1];
    h8 xA, xB;
    if (!MASK || ok){
      xA = *reinterpret_cast<const h8*>(xl + sA * DO + cbase);
      xB = *reinterpret_cast<const h8*>(xl + sB * DO + cbase);
    } else { xA = hzero(); xB = hzero(); }
    float pA = edge_logit(xA, xrv, attv);
    float pB = edge_logit(xB, xrv, attv);
    gsum2<LPG>(pA, pB);
    float wA = __expf(pA), wB = __expf(pB);
    denA += wA; denB += wB;
    f8 fA = __builtin_convertvector(xA, f8);
    f8 fB = __builtin_convertvector(xB, f8);
#pragma unroll
    for (int j = 0; j < 8; j++){
      accA[j] = fmaf(wA, fA[j], accA[j]);
      accB[j] = fmaf(wB, fB[j], accB[j]);
    }
  }
  if (e < e1){
    int sA = csr_src[e];
    h8 xA = (!MASK || ok) ? *reinterpret_cast<const h8*>(xl + sA * DO + cbase) : hzero();
    float pA = gsum<LPG>(edge_logit(xA, xrv, attv));
    float w = __expf(pA);
    denA += w;
    f8 fA = __builtin_convertvector(xA, f8);
#pragma unroll
    for (int j = 0; j < 8; j++) accA[j] = fmaf(w, fA[j], accA[j]);
  }
}

// ---------------- Fused agg(layer l) + gemm(layer l+1), degree-sorted --------
// Requires LPG*8 == DO. Block = 4 waves = NPB nodes taken from perm[] (degree-
// sorted -> balanced waves & cheap barrier). agg writes h rows + node IDs to
// LDS; waves then compute the next layer's dual GEMM from LDS, storing through
// the perm table.
template<int DO, int LPG, int DO2>
__global__ __launch_bounds__(256) void agg_gemm(
    const _Float16* __restrict__ xl, const _Float16* __restrict__ xr,
    const int* __restrict__ csr_src, const int* __restrict__ row_ptr,
    const int* __restrict__ perm,
    const float* __restrict__ att, const float* __restrict__ bias,
    const _Float16* __restrict__ Wpl2, const float* __restrict__ bl2,
    const _Float16* __restrict__ Wpr2, const float* __restrict__ br2,
    _Float16* __restrict__ Yl, _Float16* __restrict__ Yr)
{
  constexpr int G = 64 / LPG;
  constexpr int NPB = 4 * G;            // nodes per block
  constexpr int LK = DO + 8;            // padded LDS row stride (halves)
  constexpr int KC2 = DO / 32;
  constexpr int NT2 = (DO2 + 15) / 16;
  constexpr int MT = NPB / 16;          // m-tiles per block (1 or 2)
  __shared__ _Float16 hs[NPB * LK];
  __shared__ int pn[NPB];

  int lane = threadIdx.x & 63;
  int wid  = threadIdx.x >> 6;
  int g = lane / LPG, p = lane % LPG;
  int nodeLocal = wid * G + g;
  int idx = blockIdx.x * NPB + nodeLocal;
  int cbase = p * 8;
  int node = (idx < NN) ? perm[idx] : NN;
  bool nvalid = node < NN;
  int nodeC = nvalid ? node : 0;
  if (p == 0) pn[nodeLocal] = node;

  // ---- agg phase ----
  h8 attv, xrv, xlv;
  {
    float4 a0 = *reinterpret_cast<const float4*>(att + cbase);
    float4 a1 = *reinterpret_cast<const float4*>(att + cbase + 4);
    attv[0]=(_Float16)a0.x; attv[1]=(_Float16)a0.y; attv[2]=(_Float16)a0.z; attv[3]=(_Float16)a0.w;
    attv[4]=(_Float16)a1.x; attv[5]=(_Float16)a1.y; attv[6]=(_Float16)a1.z; attv[7]=(_Float16)a1.w;
    xrv = *reinterpret_cast<const h8*>(xr + nodeC * DO + cbase);
    xlv = *reinterpret_cast<const h8*>(xl + nodeC * DO + cbase);
  }
  float s = gsum<LPG>(edge_logit(xlv, xrv, attv));
  float wS = __expf(s);
  float denA = wS, denB = 0.f;
  float accA[8], accB[8];
  {
    f8 xf = __builtin_convertvector(xlv, f8);
#pragma unroll
    for (int j = 0; j < 8; j++){ accA[j] = wS * xf[j]; accB[j] = 0.f; }
  }

  int e0 = row_ptr[nodeC];
  int e1 = nvalid ? row_ptr[nodeC + 1] : e0;
  agg_edges<DO, LPG, false>(xl, csr_src, e0, e1, cbase, true, xrv, attv,
                            denA, denB, accA, accB);

  {
    float inv = nvalid ? 1.0f / (denA + denB) : 0.f;
    f8 vv;
#pragma unroll
    for (int j = 0; j < 8; j++)
      vv[j] = nvalid ? fmaxf(fmaf(accA[j] + accB[j], inv, bias[cbase + j]), 0.f) : 0.f;
    h8 ho = __builtin_convertvector(vv, h8);
    *reinterpret_cast<h8*>(&hs[nodeLocal * LK + cbase]) = ho;
  }
  __syncthreads();

  // ---- gemm phase: next layer, A from LDS, stores through perm ----
  int arow = lane & 15;
  int koff = lane >> 4;
  int mt = (MT == 1) ? 0 : (wid >> 1);
  h8 afrag[KC2];
#pragma unroll
  for (int c = 0; c < KC2; c++)
    afrag[c] = *reinterpret_cast<const h8*>(&hs[(mt * 16 + arow) * LK + koff * 8 + c * 32]);

  int side = wid & 1;
  const _Float16* Wp = side ? Wpr2 : Wpl2;
  const float* bias2 = side ? br2 : bl2;
  _Float16* Y = side ? Yr : Yl;
  int nt_begin = (MT == 1) ? (wid >> 1) * (NT2 / 2) : 0;
  int nt_end   = (MT == 1) ? nt_begin + NT2 / 2 : NT2;
  int prow[4];
#pragma unroll
  for (int r = 0; r < 4; r++) prow[r] = pn[mt * 16 + koff * 4 + r];
  for (int nt = nt_begin; nt < nt_end; nt++){
    v4f acc2 = {0.f, 0.f, 0.f, 0.f};
#pragma unroll
    for (int c = 0; c < KC2; c++){
      h8 b = *reinterpret_cast<const h8*>(Wp + (size_t)((nt * KC2 + c) * 64 + lane) * 8);
      acc2 = __builtin_amdgcn_mfma_f32_16x16x32_f16(afrag[c], b, acc2, 0, 0, 0);
    }
    int col = nt * 16 + arow;
    if (col < DO2){
      float bv = bias2[col];
#pragma unroll
      for (int r = 0; r < 4; r++){
        if (prow[r] < NN) Y[(size_t)prow[r] * DO2 + col] = (_Float16)(acc2[r] + bv);
      }
    }
  }
}

// ---------------- Final GATv2 aggregate + bias + log_softmax (degree-sorted) --
template<int DO, int LPG>
__global__ __launch_bounds__(256) void gat_agg_out(
    const _Float16* __restrict__ xl, const _Float16* __restrict__ xr,
    const int* __restrict__ csr_src, const int* __restrict__ row_ptr,
    const int* __restrict__ perm,
    const float* __restrict__ att, const float* __restrict__ bias,
    float* __restrict__ out)
{
  constexpr int G = 64 / LPG;
  int lane = threadIdx.x & 63;
  int wv = (blockIdx.x * 256 + threadIdx.x) >> 6;
  int g = lane / LPG;
  int p = lane % LPG;
  int idx = wv * G + g;
  if (idx >= NN) return;
  int node = perm[idx];
  int cbase = p * 8;
  bool ok = (cbase < DO);

  h8 attv = hzero(), xrv = hzero(), xlv = hzero();
  if (ok){
    float4 a0 = *reinterpret_cast<const float4*>(att + cbase);
    float4 a1 = *reinterpret_cast<const float4*>(att + cbase + 4);
    attv[0]=(_Float16)a0.x; attv[1]=(_Float16)a0.y; attv[2]=(_Float16)a0.z; attv[3]=(_Float16)a0.w;
    attv[4]=(_Float16)a1.x; attv[5]=(_Float16)a1.y; attv[6]=(_Float16)a1.z; attv[7]=(_Float16)a1.w;
    xrv = *reinterpret_cast<const h8*>(xr + node * DO + cbase);
    xlv = *reinterpret_cast<const h8*>(xl + node * DO + cbase);
  }

  float s = gsum<LPG>(edge_logit(xlv, xrv, attv));
  float wS = __expf(s);
  float denA = wS, denB = 0.f;
  float accA[8], accB[8];
  {
    f8 xf = __builtin_convertvector(xlv, f8);
#pragma unroll
    for (int j = 0; j < 8; j++){ accA[j] = wS * xf[j]; accB[j] = 0.f; }
  }

  int e0 = row_ptr[node], e1 = row_ptr[node + 1];
  agg_edges<DO, LPG, true>(xl, csr_src, e0, e1, cbase, ok, xrv, attv,
                           denA, denB, accA, accB);

  float inv = 1.0f / (denA + denB);
  float v[8]; float lmax = NEGX;
#pragma unroll
  for (int j = 0; j < 8; j++){
    v[j] = ok ? fmaf(accA[j] + accB[j], inv, bias[cbase + j]) : NEGX;
    lmax = fmaxf(lmax, v[j]);
  }
  lmax = gmax<LPG>(lmax);
  float lsum = 0.f;
#pragma unroll
  for (int j = 0; j < 8; j++) lsum += __expf(v[j] - lmax);   // idle lanes: exp(NEGX)=0
  lsum = gsum<LPG>(lsum);
  if (ok){
    float lg = lmax + __logf(lsum);
    float* op = (float*)out + (size_t)node * DO + cbase;
    float4 o0, o1;
    o0.x = v[0] - lg; o0.y = v[1] - lg; o0.z = v[2] - lg; o0.w = v[3] - lg;
    o1.x = v[4] - lg; o1.y = v[5] - lg; o1.z = v[6] - lg; o1.w = v[7] - lg;
    *reinterpret_cast<float4*>(op) = o0;
    *reinterpret_cast<float4*>(op + 4) = o1;
  }
}

extern "C" void kernel_launch(void* const* d_in, const int* in_sizes, int n_in,
                              void* d_out, int out_size, void* d_ws, size_t ws_size,
                              hipStream_t stream) {
  const float* x   = (const float*)d_in[0];
  const int*   ei  = (const int*)d_in[1];
  const float* W1l = (const float*)d_in[2];  const float* W1r = (const float*)d_in[3];
  const float* b1l = (const float*)d_in[4];  const float* b1r = (const float*)d_in[5];
  const float* a1  = (const float*)d_in[6];  const float* c1  = (const float*)d_in[7];
  const float* W2l = (const float*)d_in[8];  const float* W2r = (const float*)d_in[9];
  const float* b2l = (const float*)d_in[10]; const float* b2r = (const float*)d_in[11];
  const float* a2  = (const float*)d_in[12]; const float* c2  = (const float*)d_in[13];
  const float* W3l = (const float*)d_in[14]; const float* W3r = (const float*)d_in[15];
  const float* b3l = (const float*)d_in[16]; const float* b3r = (const float*)d_in[17];
  const float* a3  = (const float*)d_in[18]; const float* c3  = (const float*)d_in[19];
  float* outp = (float*)d_out;

  // workspace layout (16B-aligned segments)
  _Float16* xl1 = (_Float16*)d_ws;        // 50000*128
  _Float16* xr1 = xl1 + 6400000;
  _Float16* xl2 = xr1 + 6400000;          // 50000*64
  _Float16* xr2 = xl2 + 3200000;
  _Float16* xl3 = xr2 + 3200000;          // 50000*40
  _Float16* xr3 = xl3 + 2000000;
  _Float16* wp1l = xr3 + 2000000;         // packed weights (fp16)
  _Float16* wp1r = wp1l + 32768;
  _Float16* wp2l = wp1r + 32768;
  _Float16* wp2r = wp2l + 8192;
  _Float16* wp3l = wp2r + 8192;
  _Float16* wp3r = wp3l + 3072;
  unsigned* pk   = (unsigned*)(wp3r + 3072);   // 800000
  int* csr_src   = (int*)(pk + NE);            // 800000
  int* row_ptr   = csr_src + NE;               // 50001
  int* gbp       = row_ptr + 50001;            // 64*256 partial hist
  int* base      = gbp + 16384;                // 257
  int* bcur      = base + 257;                 // 256
  int* dhist     = bcur + 256;                 // 64
  int* dcur      = dhist + 64;                 // 64
  int* perm      = dcur + 64;                  // 50000

  const int GB = (NN + 63) / 64;          // 782 gemm1 blocks (64 rows, 4 waves)
  const int SB = (NE + CH - 1) / CH;      // 98 scatter blocks
  const int NB = (NN + 255) / 256;        // 196 node blocks
  const int FB1 = (NN + 15) / 16;         // fused agg1+gemm2: 16 nodes/block
  const int FB2 = (NN + 31) / 32;         // fused agg2+gemm3: 32 nodes/block
  const int AB3 = (NN + 31) / 32;         // agg3: 32 nodes/block (LPG=8)

  // pack weights + partial edge histogram (one launch)
  k_pack_hist<<<108, 256, 0, stream>>>(W1l, W1r, W2l, W2r, W3l, W3r,
                                       wp1l, wp1r, wp2l, wp2r, wp3l, wp3r,
                                       ei, gbp);
  k_scan<<<1, 256, 0, stream>>>(gbp, base, bcur, row_ptr, dhist);
  k_bscatter<<<SB, 256, 0, stream>>>(ei, bcur, pk);
  k_bcsr<<<NB, 256, 0, stream>>>(pk, base, row_ptr, csr_src, dhist);
  // degree sort: 64-bin scan + counting scatter -> perm
  k_dscan<<<1, 64, 0, stream>>>(dhist, dcur);
  k_dscatter<<<NB, 256, 0, stream>>>(row_ptr, dcur, perm);

  // layer 1 GEMM: x (fp32) -> xl1, xr1
  gemm_direct<float,256,128><<<GB, 256, 0, stream>>>(x, wp1l, b1l, wp1r, b1r, xl1, xr1);

  // fused: agg layer1 (relu) + gemm layer2 -> xl2, xr2
  agg_gemm<128,16,64><<<FB1, 256, 0, stream>>>(xl1, xr1, csr_src, row_ptr, perm,
                                               a1, c1, wp2l, b2l, wp2r, b2r, xl2, xr2);

  // fused: agg layer2 (relu) + gemm layer3 -> xl3, xr3
  agg_gemm<64,8,40><<<FB2, 256, 0, stream>>>(xl2, xr2, csr_src, row_ptr, perm,
                                             a2, c2, wp3l, b3l, wp3r, b3r, xl3, xr3);

  // final: agg layer3 + bias + log_softmax -> out
  gat_agg_out<40,8><<<AB3, 256, 0, stream>>>(xl3, xr3, csr_src, row_ptr, perm,
                                             a3, c3, outp);
}

// Round 12
// 296.245 us; speedup vs baseline: 1.0164x; 1.0006x over previous
//
#include <hip/hip_runtime.h>
#include <math.h>

#define NN 50000
#define NE 800000
#define SLOPE 0.2f
#define NEGX (-1e30f)
#define CH 8192

typedef _Float16 h8 __attribute__((ext_vector_type(8)));
typedef _Float16 h2 __attribute__((ext_vector_type(2)));
typedef float f8 __attribute__((ext_vector_type(8)));
typedef float v4f __attribute__((ext_vector_type(4)));

__device__ __forceinline__ h8 hzero(){ h8 z = {0,0,0,0,0,0,0,0}; return z; }

// ---------------- fused weight pack (fp16 fragment order) + edge histogram ----
__device__ __forceinline__ void pack_one(const float* __restrict__ W,
                                         _Float16* __restrict__ Wp,
                                         int DO, int K, int NT, int t){
  int KC = K >> 5;
  if (t >= NT * KC * 64) return;
  int lane = t & 63;
  int rest = t >> 6;
  int c  = rest % KC;
  int nt = rest / KC;
  int col = nt * 16 + (lane & 15);
  int k0  = c * 32 + ((lane >> 4) << 3);
  _Float16 o[8];
#pragma unroll
  for (int j = 0; j < 8; j++){
    float v = (col < DO) ? W[(k0 + j) * DO + col] : 0.f;
    o[j] = (_Float16)v;
  }
  *(ulonglong2*)(Wp + (size_t)t * 8) = *(ulonglong2*)o;
}

__global__ __launch_bounds__(256) void k_pack_hist(
    const float* W1l, const float* W1r, const float* W2l,
    const float* W2r, const float* W3l, const float* W3r,
    _Float16* p1l, _Float16* p1r, _Float16* p2l,
    _Float16* p2r, _Float16* p3l, _Float16* p3r,
    const int* __restrict__ ei, int* __restrict__ gbp){
  __shared__ int h[256];
  int b = blockIdx.x, t = threadIdx.x;
  if (b < 44){
    if      (b < 16) pack_one(W1l, p1l, 128, 256, 8, (b     ) * 256 + t);
    else if (b < 32) pack_one(W1r, p1r, 128, 256, 8, (b - 16) * 256 + t);
    else if (b < 36) pack_one(W2l, p2l,  64, 128, 4, (b - 32) * 256 + t);
    else if (b < 40) pack_one(W2r, p2r,  64, 128, 4, (b - 36) * 256 + t);
    else if (b < 42) pack_one(W3l, p3l,  40,  64, 3, (b - 40) * 256 + t);
    else             pack_one(W3r, p3r,  40,  64, 3, (b - 42) * 256 + t);
  } else {
    int hb = b - 44;                 // 0..63, each owns 12500 edges
    h[t] = 0;
    __syncthreads();
    int e0 = hb * 12500;
    for (int i = t; i < 12500; i += 256)
      atomicAdd(&h[ei[NE + e0 + i] >> 8], 1);
    __syncthreads();
    gbp[hb * 256 + t] = h[t];        // non-atomic partials
  }
}

__global__ __launch_bounds__(256) void k_scan(const int* __restrict__ gbp,
                                              int* __restrict__ base,
                                              int* __restrict__ bcur,
                                              int* __restrict__ row_ptr,
                                              int* __restrict__ dhist){
  __shared__ int s[256];
  int t = threadIdx.x;
  if (t < 64) dhist[t] = 0;          // zero degree-histogram for k_bcsr
  int v = 0;
#pragma unroll 8
  for (int i = 0; i < 64; i++) v += gbp[i * 256 + t];
  s[t] = v; __syncthreads();
  for (int off = 1; off < 256; off <<= 1){
    int a = (t >= off) ? s[t - off] : 0;
    __syncthreads(); s[t] += a; __syncthreads();
  }
  int ex = s[t] - v;
  base[t] = ex;
  bcur[t] = ex;
  if (t == 255){ base[256] = s[255]; row_ptr[NN] = s[255]; }
}

// pack: src (16b) | dstLow (8b) << 16 | bucket (8b) << 24
__global__ __launch_bounds__(256) void k_bscatter(const int* __restrict__ ei,
                                                  int* __restrict__ bcur,
                                                  unsigned* __restrict__ pk_out){
  __shared__ unsigned pk[CH];
  __shared__ int h[256];
  int t = threadIdx.x;
  int e0 = blockIdx.x * CH;
  h[t] = 0;
  __syncthreads();
  int n = NE - e0; if (n > CH) n = CH;
  for (int i = t; i < n; i += 256){
    int e = e0 + i;
    int s = ei[e], d = ei[NE + e];
    pk[i] = (unsigned)s | ((unsigned)(d & 255) << 16) | ((unsigned)(d >> 8) << 24);
    atomicAdd(&h[d >> 8], 1);
  }
  __syncthreads();
  int c = h[t];
  if (c) h[t] = atomicAdd(&bcur[t], c);
  __syncthreads();
  for (int i = t; i < n; i += 256){
    unsigned u = pk[i];
    int pos = atomicAdd(&h[u >> 24], 1);
    pk_out[pos] = u;
  }
}

__global__ __launch_bounds__(256) void k_bcsr(const unsigned* __restrict__ pk,
                                              const int* __restrict__ base,
                                              int* __restrict__ row_ptr,
                                              int* __restrict__ csr_src,
                                              int* __restrict__ dhist){
  __shared__ int h[256], s[256], dh[64];
  int t = threadIdx.x;
  int b = blockIdx.x;
  int lo = base[b], hi = base[b + 1];
  h[t] = 0;
  if (t < 64) dh[t] = 0;
  __syncthreads();
  for (int i = lo + t; i < hi; i += 256)
    atomicAdd(&h[(pk[i] >> 16) & 255], 1);
  __syncthreads();
  int v = h[t];
  s[t] = v; __syncthreads();
  for (int off = 1; off < 256; off <<= 1){
    int a = (t >= off) ? s[t - off] : 0;
    __syncthreads(); s[t] += a; __syncthreads();
  }
  int ex = lo + s[t] - v;
  int node = b * 256 + t;
  if (node < NN){
    row_ptr[node] = ex;
    atomicAdd(&dh[v < 63 ? v : 63], 1);   // degree histogram (block-local)
  }
  h[t] = ex;
  __syncthreads();
  if (t < 64 && dh[t]) atomicAdd(&dhist[t], dh[t]);
  for (int i = lo + t; i < hi; i += 256){
    unsigned u = pk[i];
    int pos = atomicAdd(&h[(u >> 16) & 255], 1);
    csr_src[pos] = (int)(u & 0xFFFFu);
  }
}

// scan the 64-bin degree histogram -> DESCENDING cursors (heavy nodes first:
// longest-processing-time-first removes the straggler tail)
__global__ __launch_bounds__(64) void k_dscan(const int* __restrict__ dhist,
                                              int* __restrict__ dcur){
  __shared__ int s[64];
  int t = threadIdx.x;
  int v = dhist[t];
  s[t] = v; __syncthreads();
  for (int off = 1; off < 64; off <<= 1){
    int a = (t >= off) ? s[t - off] : 0;
    __syncthreads(); s[t] += a; __syncthreads();
  }
  dcur[t] = s[63] - s[t];    // bins > t come first
}

// counting-sort node IDs by (clamped) degree -> perm
__global__ __launch_bounds__(256) void k_dscatter(const int* __restrict__ row_ptr,
                                                  int* __restrict__ dcur,
                                                  int* __restrict__ perm){
  __shared__ int dh[64];
  int t = threadIdx.x;
  int node = blockIdx.x * 256 + t;
  int bin = -1, rank = 0;
  if (t < 64) dh[t] = 0;
  __syncthreads();
  if (node < NN){
    int deg = row_ptr[node + 1] - row_ptr[node];
    bin = deg < 63 ? deg : 63;
    rank = atomicAdd(&dh[bin], 1);
  }
  __syncthreads();
  if (t < 64){ int c = dh[t]; dh[t] = c ? atomicAdd(&dcur[t], c) : 0; }
  __syncthreads();
  if (bin >= 0) perm[dh[bin] + rank] = node;
}

// ---------------- Direct-load MFMA dual GEMM (no LDS, no barrier) -------------
template<typename TI, int K, int DO>
__global__ __launch_bounds__(256, 4) void gemm_direct(
    const TI* __restrict__ X,
    const _Float16* __restrict__ Wpl, const float* __restrict__ bl,
    const _Float16* __restrict__ Wpr, const float* __restrict__ br,
    _Float16* __restrict__ Yl, _Float16* __restrict__ Yr)
{
  constexpr int KC = K / 32;
  constexpr int NT = (DO + 15) / 16;
  int lane = threadIdx.x & 63;
  int wv   = threadIdx.x >> 6;
  int row0 = (blockIdx.x * 4 + wv) * 16;   // m-tile base
  int arow = lane & 15;
  int koff = lane >> 4;
  int lrow = row0 + arow;
  int crow = (lrow < NN) ? lrow : 0;       // clamp loads; stores masked

  h8 afrag[KC];
  if constexpr (sizeof(TI) == 4){
    const float* Xr = (const float*)X + (size_t)crow * K + koff * 8;
#pragma unroll
    for (int c = 0; c < KC; c++){
      float4 v0 = *reinterpret_cast<const float4*>(Xr + c * 32);
      float4 v1 = *reinterpret_cast<const float4*>(Xr + c * 32 + 4);
      h8 a;
      a[0]=(_Float16)v0.x; a[1]=(_Float16)v0.y; a[2]=(_Float16)v0.z; a[3]=(_Float16)v0.w;
      a[4]=(_Float16)v1.x; a[5]=(_Float16)v1.y; a[6]=(_Float16)v1.z; a[7]=(_Float16)v1.w;
      afrag[c] = a;
    }
  } else {
    const _Float16* Xr = (const _Float16*)X + (size_t)crow * K + koff * 8;
#pragma unroll
    for (int c = 0; c < KC; c++)
      afrag[c] = *reinterpret_cast<const h8*>(Xr + c * 32);
  }

#pragma unroll
  for (int side = 0; side < 2; side++){
    const _Float16* Wp = side ? Wpr : Wpl;
    const float* bias = side ? br : bl;
    _Float16* Y = side ? Yr : Yl;
#pragma unroll
    for (int nt = 0; nt < NT; nt++){
      v4f acc = {0.f, 0.f, 0.f, 0.f};
#pragma unroll
      for (int c = 0; c < KC; c++){
        h8 b = *reinterpret_cast<const h8*>(Wp + (size_t)((nt * KC + c) * 64 + lane) * 8);
        acc = __builtin_amdgcn_mfma_f32_16x16x32_f16(afrag[c], b, acc, 0, 0, 0);
      }
      int col = nt * 16 + arow;            // C/D: col = lane&15
      if (col < DO){
        float bv = bias[col];
        int rbase = row0 + koff * 4;       // C/D: row = (lane>>4)*4 + reg
#pragma unroll
        for (int r = 0; r < 4; r++){
          int orow = rbase + r;
          if (orow < NN) Y[(size_t)orow * DO + col] = (_Float16)(acc[r] + bv);
        }
      }
    }
  }
}

// ---------------- agg helpers ----------------
__device__ __forceinline__ float edge_logit(h8 x, h8 xrv, h8 attv){
  h8 t = x + xrv;
  h8 l = __builtin_elementwise_max(t, t * (_Float16)SLOPE);
  const h2* lp = (const h2*)&l;
  const h2* ap = (const h2*)&attv;
  h2 d = lp[0] * ap[0];
  d += lp[1] * ap[1];
  d += lp[2] * ap[2];
  d += lp[3] * ap[3];
  return (float)d[0] + (float)d[1];
}

template<int LPG>
__device__ __forceinline__ float gsum(float v){
#pragma unroll
  for (int off = 1; off < LPG; off <<= 1) v += __shfl_xor(v, off, 64);
  return v;
}
template<int LPG>
__device__ __forceinline__ void gsum2(float& a, float& b){
#pragma unroll
  for (int off = 1; off < LPG; off <<= 1){
    a += __shfl_xor(a, off, 64);
    b += __shfl_xor(b, off, 64);
  }
}
template<int LPG>
__device__ __forceinline__ float gmax(float v){
#pragma unroll
  for (int off = 1; off < LPG; off <<= 1) v = fmaxf(v, __shfl_xor(v, off, 64));
  return v;
}

// 2-state online aggregation (no max-subtract: Glorot logits O(+-8), exp safe)
template<int DO, int LPG, bool MASK>
__device__ __forceinline__ void agg_edges(
    const _Float16* __restrict__ xl, const int* __restrict__ csr_src,
    int e0, int e1, int cbase, bool ok, h8 xrv, h8 attv,
    float& denA, float& denB, float* accA, float* accB)
{
  int e = e0;
  for (; e + 1 < e1; e += 2){
    int sA = csr_src[e], sB = csr_src[e + 1];
    h8 xA, xB;
    if (!MASK || ok){
      xA = *reinterpret_cast<const h8*>(xl + sA * DO + cbase);
      xB = *reinterpret_cast<const h8*>(xl + sB * DO + cbase);
    } else { xA = hzero(); xB = hzero(); }
    float pA = edge_logit(xA, xrv, attv);
    float pB = edge_logit(xB, xrv, attv);
    gsum2<LPG>(pA, pB);
    float wA = __expf(pA), wB = __expf(pB);
    denA += wA; denB += wB;
    f8 fA = __builtin_convertvector(xA, f8);
    f8 fB = __builtin_convertvector(xB, f8);
#pragma unroll
    for (int j = 0; j < 8; j++){
      accA[j] = fmaf(wA, fA[j], accA[j]);
      accB[j] = fmaf(wB, fB[j], accB[j]);
    }
  }
  if (e < e1){
    int sA = csr_src[e];
    h8 xA = (!MASK || ok) ? *reinterpret_cast<const h8*>(xl + sA * DO + cbase) : hzero();
    float pA = gsum<LPG>(edge_logit(xA, xrv, attv));
    float w = __expf(pA);
    denA += w;
    f8 fA = __builtin_convertvector(xA, f8);
#pragma unroll
    for (int j = 0; j < 8; j++) accA[j] = fmaf(w, fA[j], accA[j]);
  }
}

// ---------------- Fused agg(layer l) + gemm(layer l+1), degree-sorted --------
template<int DO, int LPG, int DO2>
__global__ __launch_bounds__(256, 8) void agg_gemm(
    const _Float16* __restrict__ xl, const _Float16* __restrict__ xr,
    const int* __restrict__ csr_src, const int* __restrict__ row_ptr,
    const int* __restrict__ perm,
    const float* __restrict__ att, const float* __restrict__ bias,
    const _Float16* __restrict__ Wpl2, const float* __restrict__ bl2,
    const _Float16* __restrict__ Wpr2, const float* __restrict__ br2,
    _Float16* __restrict__ Yl, _Float16* __restrict__ Yr)
{
  constexpr int G = 64 / LPG;
  constexpr int NPB = 4 * G;            // nodes per block
  constexpr int LK = DO + 8;            // padded LDS row stride (halves)
  constexpr int KC2 = DO / 32;
  constexpr int NT2 = (DO2 + 15) / 16;
  constexpr int MT = NPB / 16;          // m-tiles per block (1 or 2)
  __shared__ _Float16 hs[NPB * LK];
  __shared__ int pn[NPB];

  int lane = threadIdx.x & 63;
  int wid  = threadIdx.x >> 6;
  int g = lane / LPG, p = lane % LPG;
  int nodeLocal = wid * G + g;
  int idx = blockIdx.x * NPB + nodeLocal;
  int cbase = p * 8;
  int node = (idx < NN) ? perm[idx] : NN;
  bool nvalid = node < NN;
  int nodeC = nvalid ? node : 0;
  if (p == 0) pn[nodeLocal] = node;

  // ---- agg phase ----
  h8 attv, xrv, xlv;
  {
    float4 a0 = *reinterpret_cast<const float4*>(att + cbase);
    float4 a1 = *reinterpret_cast<const float4*>(att + cbase + 4);
    attv[0]=(_Float16)a0.x; attv[1]=(_Float16)a0.y; attv[2]=(_Float16)a0.z; attv[3]=(_Float16)a0.w;
    attv[4]=(_Float16)a1.x; attv[5]=(_Float16)a1.y; attv[6]=(_Float16)a1.z; attv[7]=(_Float16)a1.w;
    xrv = *reinterpret_cast<const h8*>(xr + nodeC * DO + cbase);
    xlv = *reinterpret_cast<const h8*>(xl + nodeC * DO + cbase);
  }
  float s = gsum<LPG>(edge_logit(xlv, xrv, attv));
  float wS = __expf(s);
  float denA = wS, denB = 0.f;
  float accA[8], accB[8];
  {
    f8 xf = __builtin_convertvector(xlv, f8);
#pragma unroll
    for (int j = 0; j < 8; j++){ accA[j] = wS * xf[j]; accB[j] = 0.f; }
  }

  int e0 = row_ptr[nodeC];
  int e1 = nvalid ? row_ptr[nodeC + 1] : e0;
  agg_edges<DO, LPG, false>(xl, csr_src, e0, e1, cbase, true, xrv, attv,
                            denA, denB, accA, accB);

  {
    float inv = nvalid ? 1.0f / (denA + denB) : 0.f;
    f8 vv;
#pragma unroll
    for (int j = 0; j < 8; j++)
      vv[j] = nvalid ? fmaxf(fmaf(accA[j] + accB[j], inv, bias[cbase + j]), 0.f) : 0.f;
    h8 ho = __builtin_convertvector(vv, h8);
    *reinterpret_cast<h8*>(&hs[nodeLocal * LK + cbase]) = ho;
  }
  __syncthreads();

  // ---- gemm phase: next layer, A from LDS, stores through perm ----
  int arow = lane & 15;
  int koff = lane >> 4;
  int mt = (MT == 1) ? 0 : (wid >> 1);
  h8 afrag[KC2];
#pragma unroll
  for (int c = 0; c < KC2; c++)
    afrag[c] = *reinterpret_cast<const h8*>(&hs[(mt * 16 + arow) * LK + koff * 8 + c * 32]);

  int side = wid & 1;
  const _Float16* Wp = side ? Wpr2 : Wpl2;
  const float* bias2 = side ? br2 : bl2;
  _Float16* Y = side ? Yr : Yl;
  int nt_begin = (MT == 1) ? (wid >> 1) * (NT2 / 2) : 0;
  int nt_end   = (MT == 1) ? nt_begin + NT2 / 2 : NT2;
  int prow[4];
#pragma unroll
  for (int r = 0; r < 4; r++) prow[r] = pn[mt * 16 + koff * 4 + r];
  for (int nt = nt_begin; nt < nt_end; nt++){
    v4f acc2 = {0.f, 0.f, 0.f, 0.f};
#pragma unroll
    for (int c = 0; c < KC2; c++){
      h8 b = *reinterpret_cast<const h8*>(Wp + (size_t)((nt * KC2 + c) * 64 + lane) * 8);
      acc2 = __builtin_amdgcn_mfma_f32_16x16x32_f16(afrag[c], b, acc2, 0, 0, 0);
    }
    int col = nt * 16 + arow;
    if (col < DO2){
      float bv = bias2[col];
#pragma unroll
      for (int r = 0; r < 4; r++){
        if (prow[r] < NN) Y[(size_t)prow[r] * DO2 + col] = (_Float16)(acc2[r] + bv);
      }
    }
  }
}

// ---------------- Final GATv2 aggregate + bias + log_softmax (degree-sorted) --
template<int DO, int LPG>
__global__ __launch_bounds__(256, 8) void gat_agg_out(
    const _Float16* __restrict__ xl, const _Float16* __restrict__ xr,
    const int* __restrict__ csr_src, const int* __restrict__ row_ptr,
    const int* __restrict__ perm,
    const float* __restrict__ att, const float* __restrict__ bias,
    float* __restrict__ out)
{
  constexpr int G = 64 / LPG;
  int lane = threadIdx.x & 63;
  int wv = (blockIdx.x * 256 + threadIdx.x) >> 6;
  int g = lane / LPG;
  int p = lane % LPG;
  int idx = wv * G + g;
  if (idx >= NN) return;
  int node = perm[idx];
  int cbase = p * 8;
  bool ok = (cbase < DO);

  h8 attv = hzero(), xrv = hzero(), xlv = hzero();
  if (ok){
    float4 a0 = *reinterpret_cast<const float4*>(att + cbase);
    float4 a1 = *reinterpret_cast<const float4*>(att + cbase + 4);
    attv[0]=(_Float16)a0.x; attv[1]=(_Float16)a0.y; attv[2]=(_Float16)a0.z; attv[3]=(_Float16)a0.w;
    attv[4]=(_Float16)a1.x; attv[5]=(_Float16)a1.y; attv[6]=(_Float16)a1.z; attv[7]=(_Float16)a1.w;
    xrv = *reinterpret_cast<const h8*>(xr + node * DO + cbase);
    xlv = *reinterpret_cast<const h8*>(xl + node * DO + cbase);
  }

  float s = gsum<LPG>(edge_logit(xlv, xrv, attv));
  float wS = __expf(s);
  float denA = wS, denB = 0.f;
  float accA[8], accB[8];
  {
    f8 xf = __builtin_convertvector(xlv, f8);
#pragma unroll
    for (int j = 0; j < 8; j++){ accA[j] = wS * xf[j]; accB[j] = 0.f; }
  }

  int e0 = row_ptr[node], e1 = row_ptr[node + 1];
  agg_edges<DO, LPG, true>(xl, csr_src, e0, e1, cbase, ok, xrv, attv,
                           denA, denB, accA, accB);

  float inv = 1.0f / (denA + denB);
  float v[8]; float lmax = NEGX;
#pragma unroll
  for (int j = 0; j < 8; j++){
    v[j] = ok ? fmaf(accA[j] + accB[j], inv, bias[cbase + j]) : NEGX;
    lmax = fmaxf(lmax, v[j]);
  }
  lmax = gmax<LPG>(lmax);
  float lsum = 0.f;
#pragma unroll
  for (int j = 0; j < 8; j++) lsum += __expf(v[j] - lmax);   // idle lanes: exp(NEGX)=0
  lsum = gsum<LPG>(lsum);
  if (ok){
    float lg = lmax + __logf(lsum);
    float* op = (float*)out + (size_t)node * DO + cbase;
    float4 o0, o1;
    o0.x = v[0] - lg; o0.y = v[1] - lg; o0.z = v[2] - lg; o0.w = v[3] - lg;
    o1.x = v[4] - lg; o1.y = v[5] - lg; o1.z = v[6] - lg; o1.w = v[7] - lg;
    *reinterpret_cast<float4*>(op) = o0;
    *reinterpret_cast<float4*>(op + 4) = o1;
  }
}

extern "C" void kernel_launch(void* const* d_in, const int* in_sizes, int n_in,
                              void* d_out, int out_size, void* d_ws, size_t ws_size,
                              hipStream_t stream) {
  const float* x   = (const float*)d_in[0];
  const int*   ei  = (const int*)d_in[1];
  const float* W1l = (const float*)d_in[2];  const float* W1r = (const float*)d_in[3];
  const float* b1l = (const float*)d_in[4];  const float* b1r = (const float*)d_in[5];
  const float* a1  = (const float*)d_in[6];  const float* c1  = (const float*)d_in[7];
  const float* W2l = (const float*)d_in[8];  const float* W2r = (const float*)d_in[9];
  const float* b2l = (const float*)d_in[10]; const float* b2r = (const float*)d_in[11];
  const float* a2  = (const float*)d_in[12]; const float* c2  = (const float*)d_in[13];
  const float* W3l = (const float*)d_in[14]; const float* W3r = (const float*)d_in[15];
  const float* b3l = (const float*)d_in[16]; const float* b3r = (const float*)d_in[17];
  const float* a3  = (const float*)d_in[18]; const float* c3  = (const float*)d_in[19];
  float* outp = (float*)d_out;

  // workspace layout (16B-aligned segments)
  _Float16* xl1 = (_Float16*)d_ws;        // 50000*128
  _Float16* xr1 = xl1 + 6400000;
  _Float16* xl2 = xr1 + 6400000;          // 50000*64
  _Float16* xr2 = xl2 + 3200000;
  _Float16* xl3 = xr2 + 3200000;          // 50000*40
  _Float16* xr3 = xl3 + 2000000;
  _Float16* wp1l = xr3 + 2000000;         // packed weights (fp16)
  _Float16* wp1r = wp1l + 32768;
  _Float16* wp2l = wp1r + 32768;
  _Float16* wp2r = wp2l + 8192;
  _Float16* wp3l = wp2r + 8192;
  _Float16* wp3r = wp3l + 3072;
  unsigned* pk   = (unsigned*)(wp3r + 3072);   // 800000
  int* csr_src   = (int*)(pk + NE);            // 800000
  int* row_ptr   = csr_src + NE;               // 50001
  int* gbp       = row_ptr + 50001;            // 64*256 partial hist
  int* base      = gbp + 16384;                // 257
  int* bcur      = base + 257;                 // 256
  int* dhist     = bcur + 256;                 // 64
  int* dcur      = dhist + 64;                 // 64
  int* perm      = dcur + 64;                  // 50000

  const int GB = (NN + 63) / 64;          // 782 gemm1 blocks (64 rows, 4 waves)
  const int SB = (NE + CH - 1) / CH;      // 98 scatter blocks
  const int NB = (NN + 255) / 256;        // 196 node blocks
  const int FB1 = (NN + 15) / 16;         // fused agg1+gemm2: 16 nodes/block
  const int FB2 = (NN + 31) / 32;         // fused agg2+gemm3: 32 nodes/block
  const int AB3 = (NN + 31) / 32;         // agg3: 32 nodes/block (LPG=8)

  // pack weights + partial edge histogram (one launch)
  k_pack_hist<<<108, 256, 0, stream>>>(W1l, W1r, W2l, W2r, W3l, W3r,
                                       wp1l, wp1r, wp2l, wp2r, wp3l, wp3r,
                                       ei, gbp);
  k_scan<<<1, 256, 0, stream>>>(gbp, base, bcur, row_ptr, dhist);
  k_bscatter<<<SB, 256, 0, stream>>>(ei, bcur, pk);
  k_bcsr<<<NB, 256, 0, stream>>>(pk, base, row_ptr, csr_src, dhist);
  // degree sort (descending): 64-bin scan + counting scatter -> perm
  k_dscan<<<1, 64, 0, stream>>>(dhist, dcur);
  k_dscatter<<<NB, 256, 0, stream>>>(row_ptr, dcur, perm);

  // layer 1 GEMM: x (fp32) -> xl1, xr1
  gemm_direct<float,256,128><<<GB, 256, 0, stream>>>(x, wp1l, b1l, wp1r, b1r, xl1, xr1);

  // fused: agg layer1 (relu) + gemm layer2 -> xl2, xr2
  agg_gemm<128,16,64><<<FB1, 256, 0, stream>>>(xl1, xr1, csr_src, row_ptr, perm,
                                               a1, c1, wp2l, b2l, wp2r, b2r, xl2, xr2);

  // fused: agg layer2 (relu) + gemm layer3 -> xl3, xr3
  agg_gemm<64,8,40><<<FB2, 256, 0, stream>>>(xl2, xr2, csr_src, row_ptr, perm,
                                             a2, c2, wp3l, b3l, wp3r, b3r, xl3, xr3);

  // final: agg layer3 + bias + log_softmax -> out
  gat_agg_out<40,8><<<AB3, 256, 0, stream>>>(xl3, xr3, csr_src, row_ptr, perm,
                                             a3, c3, outp);
}